// Round 3
// baseline (602.881 us; speedup 1.0000x reference)
//
#include <hip/hip_runtime.h>

// OuterProduct: out[b, c,    i, j] = |seq1[b,c,i] - seq2[b,c,j]|   (c in [0,64))
//               out[b, 64+c, i, j] =  seq1[b,c,i] * seq2[b,c,j]
// B=8, C=64, L=384. Output [8,128,384,384] fp32 = 604 MB; inputs 1.5 MB
// (cache-resident) -> pure write-BW bound. Roofline ~= 604 MB / 6.25 TB/s ~= 97 us.
//
// R3: grid-stride loop, 2048 blocks (8/CU), 36 iters/thread.
// Evidence trail:
//   R0 (NT store, 1 store/thread, 147k blocks): kernel ~195 us (~3.1 TB/s)
//   R2 (plain store, 2 stores/thread, 73k blocks): kernel ~185 us (~3.3 TB/s)
//   -> NT-vs-plain refuted as the 2x gap. The harness fill kernel hits
//      6.25 TB/s with FEW long-lived grid-stride waves (8 VGPR, 10% occ).
//      We were launching one workgroup per ~6 device cycles globally
//      (294,912 waves, each doing 32 B of work) — workgroup setup/teardown
//      churn leaves store pipes idle between blocks: 8 KB/block at ~1500
//      cy/block/CU = 3.3 TB/s, exactly what we measured.
// Fix: long-lived waves like the fill. Each thread: 36 grid-stride
// iterations x 2 coalesced f4 stores (lane-contiguous 1 KB/wave/stream).
//
// Index algebra per iteration: idx = ((b*64+c)*384 + i)*96 + j4
//   s1 flat index   = idx/96 = t
//   abs-half f4 off = idx + b*HALF_STRIDE_F4
//   mul-half f4 off = abs off + HALF_STRIDE_F4
// Max f4 offset = 37,748,735 < 2^31 — int math safe.

#define L_DIM 384
#define J4    96
#define HALF_STRIDE_F4 (64 * 384 * 96)   // 2,359,296 f4 elems between halves
#define NBLOCKS 2048                     // 8 blocks/CU * 256 CUs

typedef float f4 __attribute__((ext_vector_type(4)));

__global__ __launch_bounds__(256) void outer_product_kernel(
    const float* __restrict__ seq1,
    const float* __restrict__ seq2,
    float* __restrict__ out,
    int n_pairs)
{
    const int stride = NBLOCKS * 256;            // 524,288 threads total
    f4* o4 = (f4*)out;

    for (int idx = blockIdx.x * 256 + threadIdx.x; idx < n_pairs; idx += stride) {
        int t  = idx / J4;           // = (b*64+c)*384 + i  == flat s1 index
        int j4 = idx - t * J4;
        int bc = t / L_DIM;          // b*64 + c
        int b  = bc >> 6;

        float s1 = seq1[t];
        f4 s2 = *(const f4*)(seq2 + bc * L_DIM + j4 * 4);

        f4 m = s1 * s2;
        f4 d = s1 - s2;
        f4 a;
        a.x = fabsf(d.x);
        a.y = fabsf(d.y);
        a.z = fabsf(d.z);
        a.w = fabsf(d.w);

        int o = idx + b * HALF_STRIDE_F4;    // abs-half f4 offset
        o4[o]                  = a;
        o4[o + HALF_STRIDE_F4] = m;
    }
}

extern "C" void kernel_launch(void* const* d_in, const int* in_sizes, int n_in,
                              void* d_out, int out_size, void* d_ws, size_t ws_size,
                              hipStream_t stream)
{
    const float* seq1 = (const float*)d_in[0];
    const float* seq2 = (const float*)d_in[1];
    float* out = (float*)d_out;

    int n_pairs = out_size / 8;              // 18,874,368 (each iter: 2 f4)
    outer_product_kernel<<<NBLOCKS, 256, 0, stream>>>(seq1, seq2, out, n_pairs);
}